// Round 12
// baseline (412.955 us; speedup 1.0000x reference)
//
#include <hip/hip_runtime.h>
#include <hip/hip_bf16.h>

// DQNNetwork: M=65536, K=768, N=512 hidden, 3 actions. All I/O fp32.
//   h = relu(X @ Wh^T + bh)
//   d1[i,a] = dot(h[i], Wf[a,0:512]);  d2[i,a] = dot(h[i], Wf[a,512:1024])
//   out[i,a] = relu( d1 - d2/(M-1) + bf[a] + (sum_i d2[i,a])/(M-1) )
// R11: register-band fix. Unified VGPR+AGPR file steps occupancy at 128 total:
//   R8 96+64=160 -> 2 blk/CU; R9 64+64=128 -> 4 blk (but forced cap spilled);
//   R10 88+64=152 -> 2 blk. This round halves the ACC instead of the arch
//   regs: tile 128x64, 4 waves as 4m x 1n, per-wave 32x64 -> acc 2x4 frags
//   = 32 AGPRs. arch ~85 + 32 = ~117 <= 128 -> 16 waves/CU naturally, no
//   launch-bounds forcing, no spill. LDS 24KB dbuf (A 8K + B 4K per buf).
// Same verified pieces: 2-phase dbuf schedule, (r>>1)&3 swizzle (R10: 0
// conflicts), reg-staged A with cvt_pk, DMA'd B, XCD swizzle (8 consecutive
// blocks per XCD = 8 n-slots of ONE m-tile -> X rows L2-resident).
// Wh pre-converted to bf16 by a tiny kernel (0.75 MB).

#define M_DIM 65536
#define K_DIM 768
#define N_DIM 512
#define INV_NM1 (1.0f / 65535.0f)
#define OUT_ELEMS (M_DIM * 3)

typedef __attribute__((ext_vector_type(8))) short shortx8;   // 8 bf16 (4 VGPRs)
typedef __attribute__((ext_vector_type(4))) float floatx4;   // MFMA C/D
typedef __attribute__((ext_vector_type(4))) unsigned int uintx4;

__device__ __forceinline__ unsigned short f2b(float f) {
    unsigned u = __float_as_uint(f);
    unsigned r = (u + 0x7fffu + ((u >> 16) & 1u)) >> 16;   // RNE
    return (unsigned short)r;
}

#if defined(__has_builtin)
#  if __has_builtin(__builtin_amdgcn_cvt_pk_bf16_f32)
#    define HAVE_CVT_PK_BF16 1
#  endif
#endif

__device__ __forceinline__ unsigned pack2bf(float x, float y) {   // {x->lo, y->hi}, HW-verified R6
#ifdef HAVE_CVT_PK_BF16
    typedef __attribute__((ext_vector_type(2))) __bf16 bf16x2_t;
    bf16x2_t t = __builtin_amdgcn_cvt_pk_bf16_f32(x, y);
    return __builtin_bit_cast(unsigned, t);
#else
    return (unsigned)f2b(x) | ((unsigned)f2b(y) << 16);
#endif
}

// async global->LDS DMA, 16B/lane; deposits at (wave-uniform base) + lane*16.
__device__ __forceinline__ void async16(const void* g, void* l) {
    __builtin_amdgcn_global_load_lds(
        (const __attribute__((address_space(1))) void*)g,
        (__attribute__((address_space(3))) void*)l,
        16, 0, 0);
}

// ---------------------------------------------------------------------------
// Streaming fp32 -> bf16 convert (used for Wh only, 0.75 MB).
// ---------------------------------------------------------------------------
__global__ __launch_bounds__(256) void cvt_bf16_kernel(
    const float* __restrict__ src, unsigned short* __restrict__ dst, int n8)
{
    const int idx = blockIdx.x * 256 + threadIdx.x;
    if (idx >= n8) return;
    const float4 a = *(const float4*)(src + (size_t)idx * 8);
    const float4 b = *(const float4*)(src + (size_t)idx * 8 + 4);
    uint4 o;
    o.x = pack2bf(a.x, a.y); o.y = pack2bf(a.z, a.w);
    o.z = pack2bf(b.x, b.y); o.w = pack2bf(b.z, b.w);
    *(uint4*)(dst + (size_t)idx * 8) = o;
}

// ---------------------------------------------------------------------------
// Fused GEMM + head. 128x64 tile, 4 waves (4m x 1n, 32x64 each), BK=32,
// 16x16x32 MFMA, acc 2x4 = 32 AGPRs/wave. Double-buffered; 24 K-steps; one
// barrier per step; 24KB LDS. Target: arch+acc <= 128 regs -> 4 blocks/CU.
// LDS layout (bf16, rows x 32): 16B chunk c of row r at slot c ^ ((r>>1)&3)
// (R10-verified: 0 bank conflicts).
// Block swizzle: b = g*64 + slot*8 + xcd; m-tile = g*8+xcd, n-slot = slot.
// Per XCD: 8 consecutive blocks = 8 n-slots of one m-tile -> X rows (384KB)
// fetched once into that XCD's L2.
// ---------------------------------------------------------------------------
__global__ __launch_bounds__(256) void gemm_fused_kernel(
    const float* __restrict__ X,              // [M,K] fp32
    const unsigned short* __restrict__ Whb,   // [N,K] bf16
    const float* __restrict__ bh,             // [N]
    const float* __restrict__ Wf,             // [3,1024]
    float* __restrict__ gsum,                 // [3], pre-zeroed
    float* __restrict__ pslice)               // [8][M*3], each elem written once
{
    __shared__ unsigned short As[2][128 * 32];  // 2 x 8 KB bf16
    __shared__ unsigned short Bs[2][64 * 32];   // 2 x 4 KB bf16  (total 24 KB)

    const int tid  = threadIdx.x;
    const int wave = tid >> 6;            // 0..3 = m-wave index
    const int lane = tid & 63;
    const int l16  = lane & 15;
    const int quad = lane >> 4;

    // XCD-aware swizzle (see header).
    const int b  = blockIdx.x;
    const int g  = b >> 6;
    const int r  = b & 63;
    const int m0 = (g * 8 + (r & 7)) * 128;
    const int n0 = ((r >> 3) & 7) * 64;

    floatx4 acc[2][4];
    #pragma unroll
    for (int i = 0; i < 2; i++)
        #pragma unroll
        for (int j = 0; j < 4; j++) {
            floatx4 z = {0.f, 0.f, 0.f, 0.f};
            acc[i][j] = z;
        }

    // A reg-staging (identical to R10): thread handles rows {u,u+32,u+64,u+96},
    // float4 chunk q of each 32-col slab; dest 16B-chunk jc=q>>1 at slot
    // jc ^ ((row>>1)&3) == jc ^ ((u>>1)&3) (stride 32). Half = q&1.
    const int u    = tid >> 3;           // 0..31
    const int q    = tid & 7;            // float4 col index within 32-col slab
    const int aoff = u * 32 + (((q >> 1) ^ ((u >> 1) & 3)) << 3) + ((q & 1) << 2);
    const float* xb = X + (size_t)(m0 + u) * K_DIM + q * 4;

    // B DMA: 4KB/tile = 4 x 1KB issues, 1 per wave. 1KB = 16 rows of 64B,
    // 4 lanes/row. Source pre-swizzled with the same (row>>1)&3 involution.
    const int uB = lane >> 2, sBch = lane & 3;
    const int hB = (uB >> 1) & 3;        // (row>>1)&3, r0 multiple of 16

    // Frag-read chunk slot: quad ^ ((read_row>>1)&3) = quad ^ ((l16>>1)&3).
    const int co = ((quad ^ ((l16 >> 1) & 3)) << 3);

    float4 av[4];

    // ---- prologue: stage tile 0 ----
    #pragma unroll
    for (int p = 0; p < 4; p++)
        av[p] = *(const float4*)(xb + (size_t)p * 32 * K_DIM);
    {
        const int r0  = wave * 16;
        const int row = r0 + uB;
        const int gch = sBch ^ hB;
        async16(Whb + (size_t)(n0 + row) * K_DIM + gch * 8, &Bs[0][r0 * 32]);
    }
    #pragma unroll
    for (int p = 0; p < 4; p++) {
        uint2 o;
        o.x = pack2bf(av[p].x, av[p].y);
        o.y = pack2bf(av[p].z, av[p].w);
        *(uint2*)(&As[0][aoff + p * 1024]) = o;
    }
    __syncthreads();

    // ---- main loop: 24 K-steps, one barrier each ----
    #pragma unroll 2
    for (int t = 0; t < 24; t++) {
        const int cur = t & 1;
        const int nxt = cur ^ 1;
        const int k1  = (t + 1) * 32;
        if (t < 23) {
            // issue next A-tile loads first, then next B-tile DMA.
            #pragma unroll
            for (int p = 0; p < 4; p++)
                av[p] = *(const float4*)(xb + (size_t)p * 32 * K_DIM + k1);
            {
                const int r0  = wave * 16;
                const int row = r0 + uB;
                const int gch = sBch ^ hB;
                async16(Whb + (size_t)(n0 + row) * K_DIM + k1 + gch * 8,
                        &Bs[nxt][r0 * 32]);
            }
        }

        // compute current tile: per wave 32 rows x 64 cols, K=32.
        {
            shortx8 afrag[2], bfrag[4];
            #pragma unroll
            for (int mt = 0; mt < 2; mt++)
                afrag[mt] = *(const shortx8*)(&As[cur][(wave * 32 + mt * 16 + l16) * 32 + co]);
            #pragma unroll
            for (int nt = 0; nt < 4; nt++)
                bfrag[nt] = *(const shortx8*)(&Bs[cur][(nt * 16 + l16) * 32 + co]);
            #pragma unroll
            for (int mt = 0; mt < 2; mt++)
                #pragma unroll
                for (int nt = 0; nt < 4; nt++)
                    acc[mt][nt] = __builtin_amdgcn_mfma_f32_16x16x32_bf16(
                        afrag[mt], bfrag[nt], acc[mt][nt], 0, 0, 0);
        }

        // finish staging A(t+1): cvt + swizzled LDS write
        if (t < 23) {
            #pragma unroll
            for (int p = 0; p < 4; p++) {
                uint2 o;
                o.x = pack2bf(av[p].x, av[p].y);
                o.y = pack2bf(av[p].z, av[p].w);
                *(uint2*)(&As[nxt][aoff + p * 1024]) = o;
            }
        }
        __syncthreads();
    }

    // ---- Epilogue. C/D layout: col = lane&15, row = quad*4 + reg. ----
    float bhv[4], wpr0[4], wpr1[4], wpr2[4], w20[4], w21[4], w22[4];
    #pragma unroll
    for (int nt = 0; nt < 4; nt++) {
        const int col = n0 + nt * 16 + l16;
        bhv[nt] = bh[col];
        w20[nt] = Wf[512 + col];
        w21[nt] = Wf[1536 + col];
        w22[nt] = Wf[2560 + col];
        wpr0[nt] = Wf[col]        - w20[nt] * INV_NM1;
        wpr1[nt] = Wf[1024 + col] - w21[nt] * INV_NM1;
        wpr2[nt] = Wf[2048 + col] - w22[nt] * INV_NM1;
    }

    float* ps = pslice + (size_t)((r >> 3) & 7) * OUT_ELEMS;

    float q0 = 0.f, q1 = 0.f, q2 = 0.f;   // partials of sum_i d2[i,a]
    #pragma unroll
    for (int mt = 0; mt < 2; mt++) {
        #pragma unroll
        for (int rg = 0; rg < 4; rg++) {
            float p0 = 0.f, p1 = 0.f, p2 = 0.f;
            #pragma unroll
            for (int nt = 0; nt < 4; nt++) {
                float v = acc[mt][nt][rg] + bhv[nt];
                v = v > 0.f ? v : 0.f;
                p0 += v * wpr0[nt];
                p1 += v * wpr1[nt];
                p2 += v * wpr2[nt];
                q0 += v * w20[nt];
                q1 += v * w21[nt];
                q2 += v * w22[nt];
            }
            #pragma unroll
            for (int off = 1; off < 16; off <<= 1) {
                p0 += __shfl_xor(p0, off, 64);
                p1 += __shfl_xor(p1, off, 64);
                p2 += __shfl_xor(p2, off, 64);
            }
            if (l16 == 0) {
                const int row = m0 + wave * 32 + mt * 16 + quad * 4 + rg;
                ps[row * 3 + 0] = p0;
                ps[row * 3 + 1] = p1;
                ps[row * 3 + 2] = p2;
            }
        }
    }
    #pragma unroll
    for (int off = 1; off < 64; off <<= 1) {
        q0 += __shfl_xor(q0, off, 64);
        q1 += __shfl_xor(q1, off, 64);
        q2 += __shfl_xor(q2, off, 64);
    }
    float* red = (float*)As;   // reuse LDS for the 48B block reduction
    if (lane == 0) { red[wave * 3 + 0] = q0; red[wave * 3 + 1] = q1; red[wave * 3 + 2] = q2; }
    __syncthreads();
    if (tid < 3)
        atomicAdd(&gsum[tid], red[tid] + red[3 + tid] + red[6 + tid] + red[9 + tid]);
}

// ---------------------------------------------------------------------------
// finalize: out[idx] = relu( sum_s pslice[s][idx] + gsum[a]*INV + bf[a] )
// ---------------------------------------------------------------------------
__global__ __launch_bounds__(256) void finalize_kernel(
    const float* __restrict__ pslice, const float* __restrict__ gsum,
    const float* __restrict__ bfb, float* __restrict__ out)
{
    const int idx = blockIdx.x * 256 + threadIdx.x;
    float s = 0.f;
    #pragma unroll
    for (int sl = 0; sl < 8; sl++)
        s += pslice[(size_t)sl * OUT_ELEMS + idx];
    const int a = idx % 3;
    const float v = s + gsum[a] * INV_NM1 + bfb[a];
    out[idx] = v > 0.f ? v : 0.f;
}

// ---------------------------------------------------------------------------
// Fallback (R5 path, HW-verified): fused fp32 register-staging GEMM.
// ---------------------------------------------------------------------------
__global__ __launch_bounds__(256) void gemm_fused_fp32_kernel(
    const float* __restrict__ X, const float* __restrict__ Wh,
    const float* __restrict__ bh, const float* __restrict__ Wf,
    float* __restrict__ gsum, float* __restrict__ pslice)
{
    __shared__ unsigned short As[128 * 64];
    __shared__ unsigned short Bs[128 * 64];

    const int tid  = threadIdx.x;
    const int wave = tid >> 6;
    const int lane = tid & 63;
    const int l16  = lane & 15;
    const int quad = lane >> 4;
    const int wm   = wave >> 1;
    const int wn   = wave & 1;

    const int b  = blockIdx.x;
    const int g  = b >> 5;
    const int r  = b & 31;
    const int m0 = (g * 8 + (r & 7)) * 128;
    const int n0 = (r >> 3) * 128;

    floatx4 acc[4][4];
    #pragma unroll
    for (int i = 0; i < 4; i++)
        #pragma unroll
        for (int j = 0; j < 4; j++) {
            floatx4 z = {0.f, 0.f, 0.f, 0.f};
            acc[i][j] = z;
        }

    const int swr = l16 & 7;

    for (int k0 = 0; k0 < K_DIM; k0 += 64) {
        #pragma unroll
        for (int p = 0; p < 8; p++) {
            const int c   = p * 256 + tid;
            const int row = c >> 4;
            const int q   = c & 15;
            const int f4  = q << 2;
            const int jch = q >> 1;
            const int off = row * 64 + ((jch ^ (row & 7)) << 3) + ((q & 1) << 2);
            const float4 av = *(const float4*)(X  + (size_t)(m0 + row) * K_DIM + k0 + f4);
            const float4 bv = *(const float4*)(Wh + (size_t)(n0 + row) * K_DIM + k0 + f4);
            uint2 a2, b2;
            a2.x = pack2bf(av.x, av.y); a2.y = pack2bf(av.z, av.w);
            b2.x = pack2bf(bv.x, bv.y); b2.y = pack2bf(bv.z, bv.w);
            *(uint2*)(As + off) = a2;
            *(uint2*)(Bs + off) = b2;
        }
        __syncthreads();

        #pragma unroll
        for (int kk = 0; kk < 64; kk += 32) {
            shortx8 afrag[4], bfrag[4];
            const int jq = (kk >> 3) + quad;
            const int co = ((jq ^ swr) << 3);
            #pragma unroll
            for (int mt = 0; mt < 4; mt++)
                afrag[mt] = *(const shortx8*)(As + (wm * 64 + mt * 16 + l16) * 64 + co);
            #pragma unroll
            for (int nt = 0; nt < 4; nt++)
                bfrag[nt] = *(const shortx8*)(Bs + (wn * 64 + nt * 16 + l16) * 64 + co);
            #pragma unroll
            for (int mt = 0; mt < 4; mt++)
                #pragma unroll
                for (int nt = 0; nt < 4; nt++)
                    acc[mt][nt] = __builtin_amdgcn_mfma_f32_16x16x32_bf16(
                        afrag[mt], bfrag[nt], acc[mt][nt], 0, 0, 0);
        }
        __syncthreads();
    }

    float bhv[4], wpr0[4], wpr1[4], wpr2[4], w20[4], w21[4], w22[4];
    #pragma unroll
    for (int nt = 0; nt < 4; nt++) {
        const int col = n0 + wn * 64 + nt * 16 + l16;
        bhv[nt] = bh[col];
        w20[nt] = Wf[512 + col];
        w21[nt] = Wf[1536 + col];
        w22[nt] = Wf[2560 + col];
        wpr0[nt] = Wf[col]        - w20[nt] * INV_NM1;
        wpr1[nt] = Wf[1024 + col] - w21[nt] * INV_NM1;
        wpr2[nt] = Wf[2048 + col] - w22[nt] * INV_NM1;
    }

    float* ps = pslice + (size_t)((r >> 3) * 2 + wn) * OUT_ELEMS;

    float q0 = 0.f, q1 = 0.f, q2 = 0.f;
    #pragma unroll
    for (int mt = 0; mt < 4; mt++) {
        #pragma unroll
        for (int rg = 0; rg < 4; rg++) {
            float p0 = 0.f, p1 = 0.f, p2 = 0.f;
            #pragma unroll
            for (int nt = 0; nt < 4; nt++) {
                float v = acc[mt][nt][rg] + bhv[nt];
                v = v > 0.f ? v : 0.f;
                p0 += v * wpr0[nt];
                p1 += v * wpr1[nt];
                p2 += v * wpr2[nt];
                q0 += v * w20[nt];
                q1 += v * w21[nt];
                q2 += v * w22[nt];
            }
            #pragma unroll
            for (int off = 1; off < 16; off <<= 1) {
                p0 += __shfl_xor(p0, off, 64);
                p1 += __shfl_xor(p1, off, 64);
                p2 += __shfl_xor(p2, off, 64);
            }
            if (l16 == 0) {
                const int row = m0 + wm * 64 + mt * 16 + quad * 4 + rg;
                ps[row * 3 + 0] = p0;
                ps[row * 3 + 1] = p1;
                ps[row * 3 + 2] = p2;
            }
        }
    }
    #pragma unroll
    for (int off = 1; off < 64; off <<= 1) {
        q0 += __shfl_xor(q0, off, 64);
        q1 += __shfl_xor(q1, off, 64);
        q2 += __shfl_xor(q2, off, 64);
    }
    float* red = (float*)As;
    if (lane == 0) { red[wave * 3 + 0] = q0; red[wave * 3 + 1] = q1; red[wave * 3 + 2] = q2; }
    __syncthreads();
    if (tid < 3)
        atomicAdd(&gsum[tid], red[tid] + red[3 + tid] + red[6 + tid] + red[9 + tid]);
}

extern "C" void kernel_launch(void* const* d_in, const int* in_sizes, int n_in,
                              void* d_out, int out_size, void* d_ws, size_t ws_size,
                              hipStream_t stream) {
    const float* X   = (const float*)d_in[0];
    const float* Wh  = (const float*)d_in[1];
    const float* bh  = (const float*)d_in[2];
    const float* Wf  = (const float*)d_in[3];
    const float* bfb = (const float*)d_in[4];
    for (int i = 0; i < n_in; i++) {
        const float* p = (const float*)d_in[i];
        switch (in_sizes[i]) {
            case M_DIM * K_DIM: X   = p; break;
            case N_DIM * K_DIM: Wh  = p; break;
            case N_DIM:         bh  = p; break;
            case 3 * 2 * N_DIM: Wf  = p; break;
            case 3:             bfb = p; break;
            default: break;
        }
    }
    float* out = (float*)d_out;

    // ws layout: [gsum 2048][pslice 6.29MB][Whb 0.75MB]
    char* w = (char*)d_ws;
    float*          gsum   = (float*)w;
    float*          pslice = (float*)(w + 2048);
    unsigned short* Whb    = (unsigned short*)(w + 2048 + (size_t)8 * OUT_ELEMS * 4);
    const size_t need = 2048 + (size_t)8 * OUT_ELEMS * 4 + (size_t)N_DIM * K_DIM * 2;

    hipMemsetAsync(gsum, 0, 2048, stream);

    if (ws_size >= need) {
        cvt_bf16_kernel<<<(N_DIM * K_DIM / 8) / 256, 256, 0, stream>>>(Wh, Whb, N_DIM * K_DIM / 8);
        gemm_fused_kernel<<<4096, 256, 0, stream>>>(X, Whb, bh, Wf, gsum, pslice);
    } else {
        gemm_fused_fp32_kernel<<<2048, 256, 0, stream>>>(X, Wh, bh, Wf, gsum, pslice);
    }
    finalize_kernel<<<OUT_ELEMS / 256, 256, 0, stream>>>(pslice, gsum, bfb, out);
}

// Round 13
// 352.046 us; speedup vs baseline: 1.1730x; 1.1730x over previous
//
#include <hip/hip_runtime.h>
#include <hip/hip_bf16.h>

// DQNNetwork: M=65536, K=768, N=512 hidden, 3 actions. All I/O fp32.
//   h = relu(X @ Wh^T + bh)
//   d1[i,a] = dot(h[i], Wf[a,0:512]);  d2[i,a] = dot(h[i], Wf[a,512:1024])
//   out[i,a] = relu( d1 - d2/(M-1) + bf[a] + (sum_i d2[i,a])/(M-1) )
// R12: counted-vmcnt pipeline (T4). Post-mortems R8-R11: per-step wall is
// ~constant vs TLP (occ 21->31% made it WORSE); the stall is the per-step
// __syncthreads vmcnt(0) drain exposing A-load latency every step. This
// round keeps R8's measured-best geometry (146us: BK=64, 128x128, 64KB LDS,
// reg-staged A + cvt_pk, DMA'd B, verified swizzles, 2 blocks/CU) and ONLY
// changes the sync: raw s_barrier with counted s_waitcnt vmcnt(8) so
// A(t+2) loads stay in flight ACROSS the barrier. Each wave certifies its
// own staging (vmcnt for B(t+1), lgkmcnt(0) for ds_writes) pre-barrier.
// Wh pre-converted to bf16 by a tiny kernel (0.75 MB).

#define M_DIM 65536
#define K_DIM 768
#define N_DIM 512
#define INV_NM1 (1.0f / 65535.0f)
#define OUT_ELEMS (M_DIM * 3)

typedef __attribute__((ext_vector_type(8))) short shortx8;   // 8 bf16 (4 VGPRs)
typedef __attribute__((ext_vector_type(4))) float floatx4;   // MFMA C/D
typedef __attribute__((ext_vector_type(4))) unsigned int uintx4;

__device__ __forceinline__ unsigned short f2b(float f) {
    unsigned u = __float_as_uint(f);
    unsigned r = (u + 0x7fffu + ((u >> 16) & 1u)) >> 16;   // RNE
    return (unsigned short)r;
}

#if defined(__has_builtin)
#  if __has_builtin(__builtin_amdgcn_cvt_pk_bf16_f32)
#    define HAVE_CVT_PK_BF16 1
#  endif
#endif

__device__ __forceinline__ unsigned pack2bf(float x, float y) {   // {x->lo, y->hi}, HW-verified R6
#ifdef HAVE_CVT_PK_BF16
    typedef __attribute__((ext_vector_type(2))) __bf16 bf16x2_t;
    bf16x2_t t = __builtin_amdgcn_cvt_pk_bf16_f32(x, y);
    return __builtin_bit_cast(unsigned, t);
#else
    return (unsigned)f2b(x) | ((unsigned)f2b(y) << 16);
#endif
}

// async global->LDS DMA, 16B/lane; deposits at (wave-uniform base) + lane*16.
__device__ __forceinline__ void async16(const void* g, void* l) {
    __builtin_amdgcn_global_load_lds(
        (const __attribute__((address_space(1))) void*)g,
        (__attribute__((address_space(3))) void*)l,
        16, 0, 0);
}

// compiler-level memory-order pin (no instruction emitted)
__device__ __forceinline__ void mem_pin() { asm volatile("" ::: "memory"); }

// ---------------------------------------------------------------------------
// Streaming fp32 -> bf16 convert (used for Wh only, 0.75 MB).
// ---------------------------------------------------------------------------
__global__ __launch_bounds__(256) void cvt_bf16_kernel(
    const float* __restrict__ src, unsigned short* __restrict__ dst, int n8)
{
    const int idx = blockIdx.x * 256 + threadIdx.x;
    if (idx >= n8) return;
    const float4 a = *(const float4*)(src + (size_t)idx * 8);
    const float4 b = *(const float4*)(src + (size_t)idx * 8 + 4);
    uint4 o;
    o.x = pack2bf(a.x, a.y); o.y = pack2bf(a.z, a.w);
    o.z = pack2bf(b.x, b.y); o.w = pack2bf(b.z, b.w);
    *(uint4*)(dst + (size_t)idx * 8) = o;
}

// ---------------------------------------------------------------------------
// Fused GEMM + head. 128x128 tile, 4 waves (2x2 of 64x64), BK=64, 16x16x32.
// R8 geometry + counted-vmcnt schedule:
//  step t: issue B(t+1) DMA -> compute(t) -> cvt+ds_write A(t+1)
//          -> issue A(t+2) loads -> s_waitcnt vmcnt(8) lgkmcnt(0)
//          -> sched_barrier -> raw s_barrier.
//  vmcnt queue at the wait (oldest first): B(t+1)x4, A(t+2)x8 = 12;
//  vmcnt(8) completes exactly B(t+1); A(t+2) stays in flight across the
//  barrier and is auto-waited (vmcnt(4)) by the compiler at next step's cvt.
// A LDS layout (bf16): 16B chunk j of row r at slot j^(r&7)  (R5-verified).
// B LDS layout: same involution via pre-swizzled DMA source (R6-verified).
// Block swizzle: 4 n-slots of an m-tile -> same XCD (R4-R6: FETCH 399->128MB).
// ---------------------------------------------------------------------------
__global__ __launch_bounds__(256, 2) void gemm_fused_kernel(
    const float* __restrict__ X,              // [M,K] fp32
    const unsigned short* __restrict__ Whb,   // [N,K] bf16
    const float* __restrict__ bh,             // [N]
    const float* __restrict__ Wf,             // [3,1024]
    float* __restrict__ gsum,                 // [3], pre-zeroed
    float* __restrict__ pslice)               // [8][M*3], each elem written once
{
    __shared__ unsigned short As[2][128 * 64];  // 2 x 16 KB bf16
    __shared__ unsigned short Bs[2][128 * 64];  // 2 x 16 KB bf16  (total 64 KB)

    const int tid  = threadIdx.x;
    const int wave = tid >> 6;
    const int lane = tid & 63;
    const int l16  = lane & 15;
    const int quad = lane >> 4;
    const int wm   = wave >> 1;
    const int wn   = wave & 1;
    const int swr  = l16 & 7;

    // XCD-aware swizzle: b = g*32 + slot*8 + xcd; m-tile = g*8+xcd, n = slot.
    const int b  = blockIdx.x;
    const int g  = b >> 5;
    const int r  = b & 31;
    const int m0 = (g * 8 + (r & 7)) * 128;
    const int n0 = (r >> 3) * 128;

    floatx4 acc[4][4];
    #pragma unroll
    for (int i = 0; i < 4; i++)
        #pragma unroll
        for (int j = 0; j < 4; j++) {
            floatx4 z = {0.f, 0.f, 0.f, 0.f};
            acc[i][j] = z;
        }

    // A reg-staging mapping (R8-verified): thread handles rows {u, u+16, ...,
    // u+112}, float4 chunk q of each. Dest chunk jc=q>>1 at slot jc^(row&7).
    const int u    = tid >> 4;           // 0..15
    const int q    = tid & 15;           // float4 col index
    const int aoff = u * 64 + (((q >> 1) ^ (u & 7)) << 3) + ((q & 1) << 2);
    const float* xb = X + (size_t)(m0 + u) * K_DIM + q * 4;

    // B DMA lane mapping: 1KB issue = 8 bf16 rows.
    const int uB = lane >> 3, sBch = lane & 7;

    float4 av[8];

    // ---- prologue ----
    #pragma unroll
    for (int p = 0; p < 8; p++)                 // A0 loads (outstanding 8)
        av[p] = *(const float4*)(xb + (size_t)p * 16 * K_DIM);
    mem_pin();
    #pragma unroll
    for (int it = 0; it < 4; it++) {            // B0 DMA (outstanding 12)
        const int j   = wave * 4 + it;
        const int r0  = j * 8;
        const int row = r0 + uB;
        const int gch = sBch ^ (row & 7);
        async16(Whb + (size_t)(n0 + row) * K_DIM + gch * 8, &Bs[0][r0 * 64]);
    }
    mem_pin();
    #pragma unroll
    for (int p = 0; p < 8; p++) {               // cvt+write A0 (auto vmcnt(4))
        uint2 o;
        o.x = pack2bf(av[p].x, av[p].y);
        o.y = pack2bf(av[p].z, av[p].w);
        *(uint2*)(&As[0][aoff + p * 1024]) = o;
    }
    mem_pin();
    #pragma unroll
    for (int p = 0; p < 8; p++)                 // A1 loads (queue: B0x4, A1x8)
        av[p] = *(const float4*)(xb + (size_t)p * 16 * K_DIM + 64);
    mem_pin();
    asm volatile("s_waitcnt vmcnt(8) lgkmcnt(0)" ::: "memory");  // B0 done
    __builtin_amdgcn_sched_barrier(0);
    __builtin_amdgcn_s_barrier();

    // ---- main loop: 12 K-steps, raw barrier + counted vmcnt each ----
    for (int t = 0; t < 12; ++t) {
        const int cur = t & 1;
        const int nxt = cur ^ 1;
        const int k1  = (t + 1) * 64;
        const int k2  = (t + 2) * 64;

        if (t < 11) {                           // issue B(t+1) into Bs[nxt]
            #pragma unroll
            for (int it = 0; it < 4; it++) {
                const int j   = wave * 4 + it;
                const int r0  = j * 8;
                const int row = r0 + uB;
                const int gch = sBch ^ (row & 7);
                async16(Whb + (size_t)(n0 + row) * K_DIM + k1 + gch * 8,
                        &Bs[nxt][r0 * 64]);
            }
            mem_pin();
        }

        // compute current tile
        #pragma unroll
        for (int kk = 0; kk < 64; kk += 32) {
            shortx8 afrag[4], bfrag[4];
            const int jq = (kk >> 3) + quad;
            const int co = ((jq ^ swr) << 3);
            #pragma unroll
            for (int mt = 0; mt < 4; mt++)
                afrag[mt] = *(const shortx8*)(&As[cur][(wm * 64 + mt * 16 + l16) * 64 + co]);
            #pragma unroll
            for (int nt = 0; nt < 4; nt++)
                bfrag[nt] = *(const shortx8*)(&Bs[cur][(wn * 64 + nt * 16 + l16) * 64 + co]);
            #pragma unroll
            for (int mt = 0; mt < 4; mt++)
                #pragma unroll
                for (int nt = 0; nt < 4; nt++)
                    acc[mt][nt] = __builtin_amdgcn_mfma_f32_16x16x32_bf16(
                        afrag[mt], bfrag[nt], acc[mt][nt], 0, 0, 0);
        }

        if (t < 11) {
            mem_pin();
            // cvt+write A(t+1): compiler auto-waits vmcnt(4) (A(t+1) oldest).
            #pragma unroll
            for (int p = 0; p < 8; p++) {
                uint2 o;
                o.x = pack2bf(av[p].x, av[p].y);
                o.y = pack2bf(av[p].z, av[p].w);
                *(uint2*)(&As[nxt][aoff + p * 1024]) = o;
            }
            mem_pin();
            if (t < 10) {
                #pragma unroll
                for (int p = 0; p < 8; p++)     // A(t+2): stays in flight
                    av[p] = *(const float4*)(xb + (size_t)p * 16 * K_DIM + k2);
                mem_pin();
                // queue: B(t+1)x4 oldest, A(t+2)x8 -> vmcnt(8) = B(t+1) done.
                asm volatile("s_waitcnt vmcnt(8) lgkmcnt(0)" ::: "memory");
            } else {
                // last staged step: only B(11)x4 outstanding.
                asm volatile("s_waitcnt vmcnt(0) lgkmcnt(0)" ::: "memory");
            }
            __builtin_amdgcn_sched_barrier(0);
            __builtin_amdgcn_s_barrier();
        }
    }

    // ---- Epilogue. C/D layout: col = lane&15, row = quad*4 + reg. ----
    float bhv[4], wpr0[4], wpr1[4], wpr2[4], w20[4], w21[4], w22[4];
    #pragma unroll
    for (int nt = 0; nt < 4; nt++) {
        const int col = n0 + wn * 64 + nt * 16 + l16;
        bhv[nt] = bh[col];
        w20[nt] = Wf[512 + col];
        w21[nt] = Wf[1536 + col];
        w22[nt] = Wf[2560 + col];
        wpr0[nt] = Wf[col]        - w20[nt] * INV_NM1;
        wpr1[nt] = Wf[1024 + col] - w21[nt] * INV_NM1;
        wpr2[nt] = Wf[2048 + col] - w22[nt] * INV_NM1;
    }

    float* ps = pslice + (size_t)((r >> 3) * 2 + wn) * OUT_ELEMS;

    float q0 = 0.f, q1 = 0.f, q2 = 0.f;   // partials of sum_i d2[i,a]
    #pragma unroll
    for (int mt = 0; mt < 4; mt++) {
        #pragma unroll
        for (int rg = 0; rg < 4; rg++) {
            float p0 = 0.f, p1 = 0.f, p2 = 0.f;
            #pragma unroll
            for (int nt = 0; nt < 4; nt++) {
                float v = acc[mt][nt][rg] + bhv[nt];
                v = v > 0.f ? v : 0.f;
                p0 += v * wpr0[nt];
                p1 += v * wpr1[nt];
                p2 += v * wpr2[nt];
                q0 += v * w20[nt];
                q1 += v * w21[nt];
                q2 += v * w22[nt];
            }
            #pragma unroll
            for (int off = 1; off < 16; off <<= 1) {
                p0 += __shfl_xor(p0, off, 64);
                p1 += __shfl_xor(p1, off, 64);
                p2 += __shfl_xor(p2, off, 64);
            }
            if (l16 == 0) {
                const int row = m0 + wm * 64 + mt * 16 + quad * 4 + rg;
                ps[row * 3 + 0] = p0;
                ps[row * 3 + 1] = p1;
                ps[row * 3 + 2] = p2;
            }
        }
    }
    #pragma unroll
    for (int off = 1; off < 64; off <<= 1) {
        q0 += __shfl_xor(q0, off, 64);
        q1 += __shfl_xor(q1, off, 64);
        q2 += __shfl_xor(q2, off, 64);
    }
    float* red = (float*)As;   // reuse LDS for the 48B block reduction
    if (lane == 0) { red[wave * 3 + 0] = q0; red[wave * 3 + 1] = q1; red[wave * 3 + 2] = q2; }
    __syncthreads();
    if (tid < 3)
        atomicAdd(&gsum[tid], red[tid] + red[3 + tid] + red[6 + tid] + red[9 + tid]);
}

// ---------------------------------------------------------------------------
// finalize: out[idx] = relu( sum_s pslice[s][idx] + gsum[a]*INV + bf[a] )
// ---------------------------------------------------------------------------
__global__ __launch_bounds__(256) void finalize_kernel(
    const float* __restrict__ pslice, const float* __restrict__ gsum,
    const float* __restrict__ bfb, float* __restrict__ out)
{
    const int idx = blockIdx.x * 256 + threadIdx.x;
    float s = 0.f;
    #pragma unroll
    for (int sl = 0; sl < 8; sl++)
        s += pslice[(size_t)sl * OUT_ELEMS + idx];
    const int a = idx % 3;
    const float v = s + gsum[a] * INV_NM1 + bfb[a];
    out[idx] = v > 0.f ? v : 0.f;
}

// ---------------------------------------------------------------------------
// Fallback (R5 path, HW-verified): fused fp32 register-staging GEMM.
// ---------------------------------------------------------------------------
__global__ __launch_bounds__(256) void gemm_fused_fp32_kernel(
    const float* __restrict__ X, const float* __restrict__ Wh,
    const float* __restrict__ bh, const float* __restrict__ Wf,
    float* __restrict__ gsum, float* __restrict__ pslice)
{
    __shared__ unsigned short As[128 * 64];
    __shared__ unsigned short Bs[128 * 64];

    const int tid  = threadIdx.x;
    const int wave = tid >> 6;
    const int lane = tid & 63;
    const int l16  = lane & 15;
    const int quad = lane >> 4;
    const int wm   = wave >> 1;
    const int wn   = wave & 1;

    const int b  = blockIdx.x;
    const int g  = b >> 5;
    const int r  = b & 31;
    const int m0 = (g * 8 + (r & 7)) * 128;
    const int n0 = (r >> 3) * 128;

    floatx4 acc[4][4];
    #pragma unroll
    for (int i = 0; i < 4; i++)
        #pragma unroll
        for (int j = 0; j < 4; j++) {
            floatx4 z = {0.f, 0.f, 0.f, 0.f};
            acc[i][j] = z;
        }

    const int swr = l16 & 7;

    for (int k0 = 0; k0 < K_DIM; k0 += 64) {
        #pragma unroll
        for (int p = 0; p < 8; p++) {
            const int c   = p * 256 + tid;
            const int row = c >> 4;
            const int q   = c & 15;
            const int f4  = q << 2;
            const int jch = q >> 1;
            const int off = row * 64 + ((jch ^ (row & 7)) << 3) + ((q & 1) << 2);
            const float4 av = *(const float4*)(X  + (size_t)(m0 + row) * K_DIM + k0 + f4);
            const float4 bv = *(const float4*)(Wh + (size_t)(n0 + row) * K_DIM + k0 + f4);
            uint2 a2, b2;
            a2.x = pack2bf(av.x, av.y); a2.y = pack2bf(av.z, av.w);
            b2.x = pack2bf(bv.x, bv.y); b2.y = pack2bf(bv.z, bv.w);
            *(uint2*)(As + off) = a2;
            *(uint2*)(Bs + off) = b2;
        }
        __syncthreads();

        #pragma unroll
        for (int kk = 0; kk < 64; kk += 32) {
            shortx8 afrag[4], bfrag[4];
            const int jq = (kk >> 3) + quad;
            const int co = ((jq ^ swr) << 3);
            #pragma unroll
            for (int mt = 0; mt < 4; mt++)
                afrag[mt] = *(const shortx8*)(As + (wm * 64 + mt * 16 + l16) * 64 + co);
            #pragma unroll
            for (int nt = 0; nt < 4; nt++)
                bfrag[nt] = *(const shortx8*)(Bs + (wn * 64 + nt * 16 + l16) * 64 + co);
            #pragma unroll
            for (int mt = 0; mt < 4; mt++)
                #pragma unroll
                for (int nt = 0; nt < 4; nt++)
                    acc[mt][nt] = __builtin_amdgcn_mfma_f32_16x16x32_bf16(
                        afrag[mt], bfrag[nt], acc[mt][nt], 0, 0, 0);
        }
        __syncthreads();
    }

    float bhv[4], wpr0[4], wpr1[4], wpr2[4], w20[4], w21[4], w22[4];
    #pragma unroll
    for (int nt = 0; nt < 4; nt++) {
        const int col = n0 + wn * 64 + nt * 16 + l16;
        bhv[nt] = bh[col];
        w20[nt] = Wf[512 + col];
        w21[nt] = Wf[1536 + col];
        w22[nt] = Wf[2560 + col];
        wpr0[nt] = Wf[col]        - w20[nt] * INV_NM1;
        wpr1[nt] = Wf[1024 + col] - w21[nt] * INV_NM1;
        wpr2[nt] = Wf[2048 + col] - w22[nt] * INV_NM1;
    }

    float* ps = pslice + (size_t)((r >> 3) * 2 + wn) * OUT_ELEMS;

    float q0 = 0.f, q1 = 0.f, q2 = 0.f;
    #pragma unroll
    for (int mt = 0; mt < 4; mt++) {
        #pragma unroll
        for (int rg = 0; rg < 4; rg++) {
            float p0 = 0.f, p1 = 0.f, p2 = 0.f;
            #pragma unroll
            for (int nt = 0; nt < 4; nt++) {
                float v = acc[mt][nt][rg] + bhv[nt];
                v = v > 0.f ? v : 0.f;
                p0 += v * wpr0[nt];
                p1 += v * wpr1[nt];
                p2 += v * wpr2[nt];
                q0 += v * w20[nt];
                q1 += v * w21[nt];
                q2 += v * w22[nt];
            }
            #pragma unroll
            for (int off = 1; off < 16; off <<= 1) {
                p0 += __shfl_xor(p0, off, 64);
                p1 += __shfl_xor(p1, off, 64);
                p2 += __shfl_xor(p2, off, 64);
            }
            if (l16 == 0) {
                const int row = m0 + wm * 64 + mt * 16 + quad * 4 + rg;
                ps[row * 3 + 0] = p0;
                ps[row * 3 + 1] = p1;
                ps[row * 3 + 2] = p2;
            }
        }
    }
    #pragma unroll
    for (int off = 1; off < 64; off <<= 1) {
        q0 += __shfl_xor(q0, off, 64);
        q1 += __shfl_xor(q1, off, 64);
        q2 += __shfl_xor(q2, off, 64);
    }
    float* red = (float*)As;
    if (lane == 0) { red[wave * 3 + 0] = q0; red[wave * 3 + 1] = q1; red[wave * 3 + 2] = q2; }
    __syncthreads();
    if (tid < 3)
        atomicAdd(&gsum[tid], red[tid] + red[3 + tid] + red[6 + tid] + red[9 + tid]);
}

extern "C" void kernel_launch(void* const* d_in, const int* in_sizes, int n_in,
                              void* d_out, int out_size, void* d_ws, size_t ws_size,
                              hipStream_t stream) {
    const float* X   = (const float*)d_in[0];
    const float* Wh  = (const float*)d_in[1];
    const float* bh  = (const float*)d_in[2];
    const float* Wf  = (const float*)d_in[3];
    const float* bfb = (const float*)d_in[4];
    for (int i = 0; i < n_in; i++) {
        const float* p = (const float*)d_in[i];
        switch (in_sizes[i]) {
            case M_DIM * K_DIM: X   = p; break;
            case N_DIM * K_DIM: Wh  = p; break;
            case N_DIM:         bh  = p; break;
            case 3 * 2 * N_DIM: Wf  = p; break;
            case 3:             bfb = p; break;
            default: break;
        }
    }
    float* out = (float*)d_out;

    // ws layout: [gsum 2048][pslice 6.29MB][Whb 0.75MB]
    char* w = (char*)d_ws;
    float*          gsum   = (float*)w;
    float*          pslice = (float*)(w + 2048);
    unsigned short* Whb    = (unsigned short*)(w + 2048 + (size_t)8 * OUT_ELEMS * 4);
    const size_t need = 2048 + (size_t)8 * OUT_ELEMS * 4 + (size_t)N_DIM * K_DIM * 2;

    hipMemsetAsync(gsum, 0, 2048, stream);

    if (ws_size >= need) {
        cvt_bf16_kernel<<<(N_DIM * K_DIM / 8) / 256, 256, 0, stream>>>(Wh, Whb, N_DIM * K_DIM / 8);
        gemm_fused_kernel<<<2048, 256, 0, stream>>>(X, Whb, bh, Wf, gsum, pslice);
    } else {
        gemm_fused_fp32_kernel<<<2048, 256, 0, stream>>>(X, Wh, bh, Wf, gsum, pslice);
    }
    finalize_kernel<<<OUT_ELEMS / 256, 256, 0, stream>>>(pslice, gsum, bfb, out);
}